// Round 4
// baseline (884.178 us; speedup 1.0000x reference)
//
#include <hip/hip_runtime.h>
#include <stdint.h>

// MGMCGCN — 3x (binary-GCN + 5-step LSTM + fc/tanh).
// Dtypes: float inputs f32, adj int32, ALL OUTPUTS f32 (ref dtype).
// Internal compute bf16 MFMA (threshold is bf16-tolerant: 8.9e-2).
// N=4096, F=H=256, K=3, T=5, G=4H=1024.
#define NN_ 4096
#define FD 256
#define HD 256
#define KC 3
#define GD 1024
#define SA 40   // padded LDS leading dim (elements): 80 B row stride, 16B-aligned

typedef __attribute__((ext_vector_type(4))) unsigned int vu4;     // 16 B
typedef __attribute__((ext_vector_type(4))) int vi4;              // 16 B
typedef __attribute__((ext_vector_type(4))) float vf4;            // 16 B
typedef __attribute__((ext_vector_type(4))) unsigned short vus4;  // 8 B
typedef __attribute__((ext_vector_type(8))) short short8;         // bf16x8 MFMA frag
typedef __attribute__((ext_vector_type(4))) float f32x4;          // MFMA acc

__device__ __forceinline__ float b2f(unsigned short u) {
    unsigned int v = ((unsigned int)u) << 16; float f; __builtin_memcpy(&f, &v, 4); return f;
}
__device__ __forceinline__ unsigned short f2b(float x) {
    unsigned int u; __builtin_memcpy(&u, &x, 4);
    u = (u + 0x7FFFu + ((u >> 16) & 1u)) >> 16;   // RNE
    return (unsigned short)u;
}
// convert 8 consecutive f32 (16B-aligned) -> 8 bf16
__device__ __forceinline__ void cvt8(const float* __restrict__ g, unsigned short* o) {
    vf4 a = *(const vf4*)g, b = *(const vf4*)(g + 4);
    o[0] = f2b(a[0]); o[1] = f2b(a[1]); o[2] = f2b(a[2]); o[3] = f2b(a[3]);
    o[4] = f2b(b[0]); o[5] = f2b(b[1]); o[6] = f2b(b[2]); o[7] = f2b(b[3]);
}
__device__ __forceinline__ float sigm(float v) { return 1.f / (1.f + __expf(-v)); }

// ---------------------------------------------------------------------------
// Pass 1: read adj (int32, [N][N][K] k-innermost), write f32 0/1 copy into the
// d_out adj region (output #2; also gemm_agg's A source), compute
// dinv[k][i] = 1/sqrt(1 + sum_j adj[i,j,k]).
// ---------------------------------------------------------------------------
__global__ __launch_bounds__(256) void adj_pass(const int* __restrict__ adj,
        float* __restrict__ adj_out, float* __restrict__ dinv) {
    const int i = blockIdx.x, t = threadIdx.x;
    const vi4* src = (const vi4*)(adj + (size_t)i * 12288);
    vf4* dst = (vf4*)(adj_out + (size_t)i * 12288);
    float s0 = 0.f, s1 = 0.f, s2 = 0.f;
#pragma unroll
    for (int it = 0; it < 12; ++it) {
        int idx = it * 256 + t;
        vi4 v = src[idx];
        float c0 = v[0] ? 1.f : 0.f, c1 = v[1] ? 1.f : 0.f;
        float c2 = v[2] ? 1.f : 0.f, c3 = v[3] ? 1.f : 0.f;
        vf4 w; w[0] = c0; w[1] = c1; w[2] = c2; w[3] = c3;
        dst[idx] = w;
        int m0 = (t + it) % 3;                 // (4*idx) % 3
        float a0 = c0 + c3;                    // residues m0, m0+1, m0+2
        if (m0 == 0)      { s0 += a0; s1 += c1; s2 += c2; }
        else if (m0 == 1) { s1 += a0; s2 += c1; s0 += c2; }
        else              { s2 += a0; s0 += c1; s1 += c2; }
    }
    __shared__ float r0[256], r1[256], r2[256];
    r0[t] = s0; r1[t] = s1; r2[t] = s2;
    __syncthreads();
    for (int off = 128; off > 0; off >>= 1) {
        if (t < off) { r0[t] += r0[t + off]; r1[t] += r1[t + off]; r2[t] += r2[t + off]; }
        __syncthreads();
    }
    if (t == 0) {
        dinv[i]            = 1.f / sqrtf(1.f + r0[0]);
        dinv[NN_ + i]      = 1.f / sqrtf(1.f + r1[0]);
        dinv[2 * NN_ + i]  = 1.f / sqrtf(1.f + r2[0]);
    }
}

// ---------------------------------------------------------------------------
// GEMM1: yT[k][h][j] = dinv[k][j] * (x @ gnn_w[k])[j][h]  (transposed store).
// x, gnn_w f32 -> bf16 at staging.
// ---------------------------------------------------------------------------
__global__ __launch_bounds__(256) void gemm_xw(const float* __restrict__ x,
        const float* __restrict__ gw, const float* __restrict__ dinv,
        unsigned short* __restrict__ yT) {
    __shared__ __align__(16) unsigned short sA[64 * SA], sB[64 * SA];
    const int bi = blockIdx.x, bj = blockIdx.y, k = blockIdx.z;
    const int t = threadIdx.x, lane = t & 63, wave = t >> 6;
    const int m = lane & 15, q = lane >> 4, ko = q * 8;
    const int h0 = bj * 64;
    f32x4 acc[4] = {};
    const float* A0 = x + (size_t)(bi * 64) * FD;
    const float* B0 = gw + (size_t)k * FD * HD;
    const int r = t >> 2, c8 = (t & 3) << 3;        // A staging: 64 rows x 32
    const int fB = t >> 3, c8B = (t & 7) << 3;      // B staging: 32 rows x 64 (transpose)
    for (int k0 = 0; k0 < FD; k0 += 32) {
        alignas(16) unsigned short tA[8], tB[8];
        cvt8(A0 + (size_t)r * FD + k0 + c8, tA);
        *(vu4*)(sA + r * SA + c8) = *(vu4*)tA;
        cvt8(B0 + (size_t)(k0 + fB) * HD + h0 + c8B, tB);
#pragma unroll
        for (int e = 0; e < 8; ++e) sB[(c8B + e) * SA + fB] = tB[e];   // sB[n][kk]
        __syncthreads();
        short8 af = *(const short8*)(sA + (wave * 16 + m) * SA + ko);
#pragma unroll
        for (int ct = 0; ct < 4; ++ct) {
            short8 bf = *(const short8*)(sB + (ct * 16 + m) * SA + ko);
            acc[ct] = __builtin_amdgcn_mfma_f32_16x16x32_bf16(af, bf, acc[ct], 0, 0, 0);
        }
        __syncthreads();
    }
    unsigned short* yTk = yT + (size_t)k * HD * NN_;
#pragma unroll
    for (int ct = 0; ct < 4; ++ct)
#pragma unroll
        for (int r2 = 0; r2 < 4; ++r2) {
            int col = h0 + ct * 16 + m;                    // h
            int row = bi * 64 + wave * 16 + q * 4 + r2;    // j
            yTk[(size_t)col * NN_ + row] = f2b(acc[ct][r2] * dinv[(size_t)k * NN_ + row]);
        }
}

// ---------------------------------------------------------------------------
// GEMM2: xt[k][i][h] = dinv_i*(sum_j a_bin[i,j,k]*y_k[j,h] + y_k[i,h]) + b[k][h]
// A = f32 adjacency from d_out ([i][j][k] interleaved), converted to bf16 at
// staging. Tile 64(i) x 128(h) x 3k, grid (2, 64); all 3 k per block so the
// interleaved A loads stay fully coalesced 16B.
// ---------------------------------------------------------------------------
__global__ __launch_bounds__(256) void gemm_agg(const float* __restrict__ adjf,
        const unsigned short* __restrict__ yT, const float* __restrict__ dinv,
        const float* __restrict__ gnnb, unsigned short* __restrict__ xt) {
    __shared__ __align__(16) unsigned short sAi[64 * 96];     // [row][j*3+k]
    __shared__ __align__(16) unsigned short sB[3][128 * SA];  // per k: [h][j]
    const int bh = blockIdx.x, bi = blockIdx.y;
    const int t = threadIdx.x, lane = t & 63, wave = t >> 6;
    const int m = lane & 15, q = lane >> 4, ko = q * 8;
    const int i0 = bi * 64, h0 = bh * 128;
    f32x4 acc[3][8] = {};
    // A staging: 6144 f32/step = 6 x (256 thr x 4 f32); j0-invariant bases
    const float* gb[6]; unsigned short* lb[6];
#pragma unroll
    for (int it = 0; it < 6; ++it) {
        int off = it * 1024 + t * 4;           // element offset in 64x96 window
        int row = off / 96, win = off % 96;
        gb[it] = adjf + (size_t)(i0 + row) * 12288 + win;
        lb[it] = sAi + off;
    }
    // B staging: per k, 128 rows x 32 j; thread -> row t>>1, j-base (t&1)*16
    const int rB = t >> 1, cb = (t & 1) << 4;
    const unsigned short* yb[3];
#pragma unroll
    for (int kk = 0; kk < 3; ++kk)
        yb[kk] = yT + ((size_t)kk * HD + h0 + rB) * NN_ + cb;

    for (int j0 = 0; j0 < NN_; j0 += 32) {
#pragma unroll
        for (int it = 0; it < 6; ++it) {
            vf4 a = *(const vf4*)(gb[it] + (size_t)j0 * 3);
            vus4 w; w[0] = f2b(a[0]); w[1] = f2b(a[1]); w[2] = f2b(a[2]); w[3] = f2b(a[3]);
            *(vus4*)lb[it] = w;
        }
#pragma unroll
        for (int kk = 0; kk < 3; ++kk) {
            *(vu4*)(&sB[kk][rB * SA + cb])     = *(const vu4*)(yb[kk] + j0);
            *(vu4*)(&sB[kk][rB * SA + cb + 8]) = *(const vu4*)(yb[kk] + j0 + 8);
        }
        __syncthreads();
#pragma unroll
        for (int kk = 0; kk < 3; ++kk) {
            const unsigned short* ap = sAi + (wave * 16 + m) * 96 + kk;
            short8 af;
#pragma unroll
            for (int e = 0; e < 8; ++e) af[e] = (short)ap[(ko + e) * 3];
#pragma unroll
            for (int ct = 0; ct < 8; ++ct) {
                short8 bf = *(const short8*)(&sB[kk][(ct * 16 + m) * SA + ko]);
                acc[kk][ct] = __builtin_amdgcn_mfma_f32_16x16x32_bf16(af, bf, acc[kk][ct], 0, 0, 0);
            }
        }
        __syncthreads();
    }
#pragma unroll
    for (int kk = 0; kk < 3; ++kk)
#pragma unroll
        for (int ct = 0; ct < 8; ++ct)
#pragma unroll
            for (int r2 = 0; r2 < 4; ++r2) {
                int col = h0 + ct * 16 + m;                  // h
                int row = i0 + wave * 16 + q * 4 + r2;       // i
                float di = dinv[(size_t)kk * NN_ + row];
                float self = b2f(yT[((size_t)kk * HD + col) * NN_ + row]);
                float v = di * (acc[kk][ct][r2] + self) + gnnb[kk * HD + col];
                xt[((size_t)kk * NN_ + row) * HD + col] = f2b(v);
            }
}

// ---------------------------------------------------------------------------
// NT GEMM: out[k][n][col] = ep(A[k][n][:] . W[k][col][:] + b1[col] + b2[col])
// A bf16 (ws), W/b f32 (inputs). gateX (COLS=1024, b_ih+b_hh) and fc (256, tanh).
// ---------------------------------------------------------------------------
__global__ __launch_bounds__(256) void gemm_nt_ep(const unsigned short* __restrict__ A,
        const float* __restrict__ W, const float* __restrict__ b1,
        const float* __restrict__ b2, unsigned short* __restrict__ outp,
        int COLS, int do_tanh) {
    __shared__ __align__(16) unsigned short sA[64 * SA], sB[64 * SA];
    const int bg = blockIdx.x, bn = blockIdx.y, k = blockIdx.z;
    const int t = threadIdx.x, lane = t & 63, wave = t >> 6;
    const int m = lane & 15, q = lane >> 4, ko = q * 8;
    f32x4 acc[4] = {};
    const unsigned short* A0 = A + ((size_t)k * NN_ + bn * 64) * HD;
    const float* W0 = W + ((size_t)k * COLS + bg * 64) * HD;
    const int r = t >> 2, c8 = (t & 3) << 3;
    for (int k0 = 0; k0 < HD; k0 += 32) {
        *(vu4*)(sA + r * SA + c8) = *(const vu4*)(A0 + (size_t)r * HD + k0 + c8);
        alignas(16) unsigned short tB[8];
        cvt8(W0 + (size_t)r * HD + k0 + c8, tB);
        *(vu4*)(sB + r * SA + c8) = *(vu4*)tB;
        __syncthreads();
        short8 af = *(const short8*)(sA + (wave * 16 + m) * SA + ko);
#pragma unroll
        for (int ct = 0; ct < 4; ++ct) {
            short8 bf = *(const short8*)(sB + (ct * 16 + m) * SA + ko);
            acc[ct] = __builtin_amdgcn_mfma_f32_16x16x32_bf16(af, bf, acc[ct], 0, 0, 0);
        }
        __syncthreads();
    }
#pragma unroll
    for (int ct = 0; ct < 4; ++ct)
#pragma unroll
        for (int r2 = 0; r2 < 4; ++r2) {
            int col = bg * 64 + ct * 16 + m;
            int row = bn * 64 + wave * 16 + q * 4 + r2;
            float v = acc[ct][r2];
            if (b1) v += b1[(size_t)k * COLS + col];
            if (b2) v += b2[(size_t)k * COLS + col];
            if (do_tanh) v = tanhf(v);
            outp[((size_t)k * NN_ + row) * COLS + col] = f2b(v);
        }
}

// ---------------------------------------------------------------------------
// One LSTM step, register-resident gates. whh f32 (converted at staging).
// Wave w owns rows w*16..w*16+15 and computes all 4 gates for a 64-col tile.
// ---------------------------------------------------------------------------
__global__ __launch_bounds__(256) void lstm_step(const unsigned short* __restrict__ hprev,
        const float* __restrict__ whh, const unsigned short* __restrict__ gateX,
        float* __restrict__ cbuf, unsigned short* __restrict__ hnext, int first) {
    __shared__ __align__(16) unsigned short sA[64 * SA];      // h_prev tile [row][k]
    __shared__ __align__(16) unsigned short sB[4][64 * SA];   // per gate: [col][k]
    const int t = threadIdx.x, lane = t & 63, wave = t >> 6;
    const int m = lane & 15, q = lane >> 4, ko = q * 8;
    const int bc = blockIdx.x, bn = blockIdx.y, k = blockIdx.z;
    const int c0 = bc * 64;
    f32x4 acc[4][4] = {};   // [gate][col-tile]
    if (!first) {
        const unsigned short* A0 = hprev + ((size_t)k * NN_ + bn * 64) * HD;
        const float* W0 = whh + (size_t)k * GD * HD;
        const int r = t >> 2, c8 = (t & 3) << 3;
        for (int k0 = 0; k0 < HD; k0 += 32) {
            *(vu4*)(sA + r * SA + c8) = *(const vu4*)(A0 + (size_t)r * HD + k0 + c8);
#pragma unroll
            for (int gt = 0; gt < 4; ++gt) {
                alignas(16) unsigned short tB[8];
                cvt8(W0 + (size_t)(gt * 256 + c0 + r) * HD + k0 + c8, tB);
                *(vu4*)(&sB[gt][r * SA + c8]) = *(vu4*)tB;
            }
            __syncthreads();
            short8 af = *(const short8*)(sA + (wave * 16 + m) * SA + ko);
#pragma unroll
            for (int gt = 0; gt < 4; ++gt)
#pragma unroll
                for (int ct = 0; ct < 4; ++ct) {
                    short8 bf = *(const short8*)(&sB[gt][(ct * 16 + m) * SA + ko]);
                    acc[gt][ct] = __builtin_amdgcn_mfma_f32_16x16x32_bf16(af, bf, acc[gt][ct], 0, 0, 0);
                }
            __syncthreads();
        }
    }
    const unsigned short* gX = gateX + ((size_t)k * NN_ + bn * 64) * GD;
    float* crow = cbuf + ((size_t)k * NN_ + bn * 64) * HD;
    unsigned short* hrow = hnext + ((size_t)k * NN_ + bn * 64) * HD;
#pragma unroll
    for (int ct = 0; ct < 4; ++ct)
#pragma unroll
        for (int r2 = 0; r2 < 4; ++r2) {
            int row = wave * 16 + q * 4 + r2;
            int col = c0 + ct * 16 + m;
            float iv = acc[0][ct][r2] + b2f(gX[(size_t)row * GD + 0 * 256 + col]);
            float fv = acc[1][ct][r2] + b2f(gX[(size_t)row * GD + 1 * 256 + col]);
            float gv = acc[2][ct][r2] + b2f(gX[(size_t)row * GD + 2 * 256 + col]);
            float ov = acc[3][ct][r2] + b2f(gX[(size_t)row * GD + 3 * 256 + col]);
            float cold = first ? 0.f : crow[(size_t)row * HD + col];
            float cn = sigm(fv) * cold + sigm(iv) * tanhf(gv);
            float hn = sigm(ov) * tanhf(cn);
            crow[(size_t)row * HD + col] = cn;
            hrow[(size_t)row * HD + col] = f2b(hn);
        }
}

// ---------------------------------------------------------------------------
// Final epilogue: pred = sig_slice(x + mean_k delta_k); res[n][f][k] = sig_slice(x + delta_k)
// x f32; delta bf16 (ws); outputs f32.
// ---------------------------------------------------------------------------
__global__ __launch_bounds__(256) void final_ep(const float* __restrict__ x,
        const unsigned short* __restrict__ delta, float* __restrict__ pred,
        float* __restrict__ res) {
    int idx = blockIdx.x * 256 + threadIdx.x;
    size_t base = (size_t)idx * 8;
    int f0 = (int)(base & 255);
    alignas(16) unsigned short d0[8], d1[8], d2[8];
    alignas(16) float pr[8], rs[24];
    vf4 xa = *(const vf4*)(x + base), xb = *(const vf4*)(x + base + 4);
    float xs[8] = { xa[0], xa[1], xa[2], xa[3], xb[0], xb[1], xb[2], xb[3] };
    *(vu4*)d0 = *(const vu4*)(delta + base);
    *(vu4*)d1 = *(const vu4*)(delta + (size_t)NN_ * FD + base);
    *(vu4*)d2 = *(const vu4*)(delta + 2 * (size_t)NN_ * FD + base);
#pragma unroll
    for (int e = 0; e < 8; ++e) {
        int f = f0 + e;
        bool sg = (f >= 10) && (f < 253);     // sigmoid slice [START, F-END)
        float xf = xs[e];
        float da = b2f(d0[e]), db = b2f(d1[e]), dc = b2f(d2[e]);
        float dm = (da + db + dc) * (1.f / 3.f);
        float p = xf + dm; if (sg) p = sigm(p);
        pr[e] = p;
        float z0 = xf + da; if (sg) z0 = sigm(z0);
        float z1 = xf + db; if (sg) z1 = sigm(z1);
        float z2 = xf + dc; if (sg) z2 = sigm(z2);
        rs[e * 3 + 0] = z0; rs[e * 3 + 1] = z1; rs[e * 3 + 2] = z2;
    }
    *(vf4*)(pred + base)     = *(vf4*)pr;
    *(vf4*)(pred + base + 4) = *(vf4*)(pr + 4);
    size_t rb = base * 3;
#pragma unroll
    for (int v = 0; v < 6; ++v)
        *(vf4*)(res + rb + v * 4) = *(vf4*)(rs + v * 4);
}

extern "C" void kernel_launch(void* const* d_in, const int* in_sizes, int n_in,
                              void* d_out, int out_size, void* d_ws, size_t ws_size,
                              hipStream_t stream) {
    const float* x    = (const float*)d_in[0];
    const float* gnnw = (const float*)d_in[1];
    const float* gnnb = (const float*)d_in[2];
    const float* wih  = (const float*)d_in[3];
    const float* whh  = (const float*)d_in[4];
    const float* bih  = (const float*)d_in[5];
    const float* bhh  = (const float*)d_in[6];
    const float* fcw  = (const float*)d_in[7];
    const float* fcb  = (const float*)d_in[8];
    const int*   adj  = (const int*)d_in[9];

    float* out = (float*)d_out;
    float* out_pred = out;                             // [N][F]
    float* out_res  = out + (size_t)NN_ * FD;          // [N][F][K]
    float* out_adj  = out + (size_t)NN_ * FD * 4;      // [N][N][K] f32 0/1

    // workspace (56.7 MB) with lifetime overlap:
    //  R1: yT (gemm_xw..gemm_agg) -> h even-step buffer (h_last after step 4)
    //  R2: xt (gemm_agg..gateX)   -> delta (fc output)
    char* ws = (char*)d_ws;
    float*          dinv  = (float*)ws;                         // 49,152 B
    unsigned short* R1    = (unsigned short*)(ws + 49152);      // 6.0 MB
    unsigned short* R2    = (unsigned short*)(ws + 6340608);    // 6.0 MB
    unsigned short* gateX = (unsigned short*)(ws + 12632064);   // 24.0 MB
    unsigned short* hA    = (unsigned short*)(ws + 37797888);   // 6.0 MB
    float*          cbuf  = (float*)(ws + 44089344);            // 12.6 MB -> ends 56,672,256
    (void)ws_size; (void)in_sizes; (void)n_in; (void)out_size;

    adj_pass<<<dim3(4096), 256, 0, stream>>>(adj, out_adj, dinv);
    gemm_xw<<<dim3(64, 4, 3), 256, 0, stream>>>(x, gnnw, dinv, R1 /*yT*/);
    gemm_agg<<<dim3(2, 64), 256, 0, stream>>>(out_adj, R1 /*yT*/, dinv, gnnb, R2 /*xt*/);
    gemm_nt_ep<<<dim3(16, 64, 3), 256, 0, stream>>>(R2 /*xt*/, wih, bih, bhh, gateX, GD, 0);
    for (int tstep = 0; tstep < 5; ++tstep) {
        unsigned short* hp = (tstep & 1) ? R1 : hA;   // even steps write R1
        unsigned short* hn = (tstep & 1) ? hA : R1;
        lstm_step<<<dim3(4, 64, 3), 256, 0, stream>>>(hp, whh, gateX, cbuf, hn, tstep == 0 ? 1 : 0);
    }
    gemm_nt_ep<<<dim3(4, 64, 3), 256, 0, stream>>>(R1 /*h_last*/, fcw, fcb, nullptr, R2 /*delta*/, FD, 1);
    final_ep<<<dim3(512), 256, 0, stream>>>(x, R2 /*delta*/, out_pred, out_res);
}

// Round 5
// 686.967 us; speedup vs baseline: 1.2871x; 1.2871x over previous
//
#include <hip/hip_runtime.h>
#include <stdint.h>

// MGMCGCN — 3x (binary-GCN + 5-step LSTM + fc/tanh).
// Dtypes: float inputs f32, adj int32, ALL OUTPUTS f32. Internal bf16 MFMA.
// N=4096, F=H=256, K=3, T=5, G=4H=1024.
#define NN_ 4096
#define FD 256
#define HD 256
#define KC 3
#define GD 1024
#define SA 40    // padded LDS leading dim (shorts): 80 B row stride
#define PAG 40   // gemm_agg LDS pitch

typedef __attribute__((ext_vector_type(4))) unsigned int vu4;     // 16 B
typedef __attribute__((ext_vector_type(4))) int vi4;              // 16 B
typedef __attribute__((ext_vector_type(4))) float vf4;            // 16 B
typedef __attribute__((ext_vector_type(4))) unsigned short vus4;  // 8 B
typedef __attribute__((ext_vector_type(8))) short short8;         // bf16x8 MFMA frag
typedef __attribute__((ext_vector_type(4))) float f32x4;          // MFMA acc

__device__ __forceinline__ float b2f(unsigned short u) {
    unsigned int v = ((unsigned int)u) << 16; float f; __builtin_memcpy(&f, &v, 4); return f;
}
__device__ __forceinline__ unsigned short f2b(float x) {
    unsigned int u; __builtin_memcpy(&u, &x, 4);
    u = (u + 0x7FFFu + ((u >> 16) & 1u)) >> 16;   // RNE
    return (unsigned short)u;
}
__device__ __forceinline__ void cvt8(const float* __restrict__ g, unsigned short* o) {
    vf4 a = *(const vf4*)g, b = *(const vf4*)(g + 4);
    o[0] = f2b(a[0]); o[1] = f2b(a[1]); o[2] = f2b(a[2]); o[3] = f2b(a[3]);
    o[4] = f2b(b[0]); o[5] = f2b(b[1]); o[6] = f2b(b[2]); o[7] = f2b(b[3]);
}
__device__ __forceinline__ float sigm(float v) { return 1.f / (1.f + __expf(-v)); }

// ---------------------------------------------------------------------------
// adj_pass: read adj int32 [N][N][K], write f32 0/1 copy to d_out adj region,
// compute dinv[k][i] = rsqrt(1 + rowsum).
// ---------------------------------------------------------------------------
__global__ __launch_bounds__(256) void adj_pass(const int* __restrict__ adj,
        float* __restrict__ adj_out, float* __restrict__ dinv) {
    const int i = blockIdx.x, t = threadIdx.x;
    const vi4* src = (const vi4*)(adj + (size_t)i * 12288);
    vf4* dst = (vf4*)(adj_out + (size_t)i * 12288);
    float s0 = 0.f, s1 = 0.f, s2 = 0.f;
#pragma unroll
    for (int it = 0; it < 12; ++it) {
        int idx = it * 256 + t;
        vi4 v = src[idx];
        float c0 = v[0] ? 1.f : 0.f, c1 = v[1] ? 1.f : 0.f;
        float c2 = v[2] ? 1.f : 0.f, c3 = v[3] ? 1.f : 0.f;
        vf4 w; w[0] = c0; w[1] = c1; w[2] = c2; w[3] = c3;
        dst[idx] = w;
        int m0 = (t + it) % 3;                 // (4*idx) % 3
        float a0 = c0 + c3;
        if (m0 == 0)      { s0 += a0; s1 += c1; s2 += c2; }
        else if (m0 == 1) { s1 += a0; s2 += c1; s0 += c2; }
        else              { s2 += a0; s0 += c1; s1 += c2; }
    }
    __shared__ float r0[256], r1[256], r2[256];
    r0[t] = s0; r1[t] = s1; r2[t] = s2;
    __syncthreads();
    for (int off = 128; off > 0; off >>= 1) {
        if (t < off) { r0[t] += r0[t + off]; r1[t] += r1[t + off]; r2[t] += r2[t + off]; }
        __syncthreads();
    }
    if (t == 0) {
        dinv[i]            = 1.f / sqrtf(1.f + r0[0]);
        dinv[NN_ + i]      = 1.f / sqrtf(1.f + r1[0]);
        dinv[2 * NN_ + i]  = 1.f / sqrtf(1.f + r2[0]);
    }
}

// ---------------------------------------------------------------------------
// wcvt: one-time f32->bf16 of [wih | whh | fcw] into contiguous wb.
// sizes: 786432 + 786432 + 196608 = 1,769,472 elems (all /8 exact).
// ---------------------------------------------------------------------------
__global__ __launch_bounds__(256) void wcvt(const float* __restrict__ wih,
        const float* __restrict__ whh, const float* __restrict__ fcw,
        unsigned short* __restrict__ wb) {
    size_t e = ((size_t)blockIdx.x * 256 + threadIdx.x) * 8;
    const float* src; size_t off;
    if (e < 786432)       { src = wih; off = e; }
    else if (e < 1572864) { src = whh; off = e - 786432; }
    else                  { src = fcw; off = e - 1572864; }
    alignas(16) unsigned short o[8];
    cvt8(src + off, o);
    *(vu4*)(wb + e) = *(vu4*)o;
}

// ---------------------------------------------------------------------------
// GEMM1: yT[k][h][j] = dinv[k][j] * (x @ gnn_w[k])[j][h] (transposed store).
// ---------------------------------------------------------------------------
__global__ __launch_bounds__(256) void gemm_xw(const float* __restrict__ x,
        const float* __restrict__ gw, const float* __restrict__ dinv,
        unsigned short* __restrict__ yT) {
    __shared__ __align__(16) unsigned short sA[64 * SA], sB[64 * SA];
    const int bi = blockIdx.x, bj = blockIdx.y, k = blockIdx.z;
    const int t = threadIdx.x, lane = t & 63, wave = t >> 6;
    const int m = lane & 15, q = lane >> 4, ko = q * 8;
    const int h0 = bj * 64;
    f32x4 acc[4] = {};
    const float* A0 = x + (size_t)(bi * 64) * FD;
    const float* B0 = gw + (size_t)k * FD * HD;
    const int r = t >> 2, c8 = (t & 3) << 3;
    const int fB = t >> 3, c8B = (t & 7) << 3;
    for (int k0 = 0; k0 < FD; k0 += 32) {
        alignas(16) unsigned short tA[8], tB[8];
        cvt8(A0 + (size_t)r * FD + k0 + c8, tA);
        *(vu4*)(sA + r * SA + c8) = *(vu4*)tA;
        cvt8(B0 + (size_t)(k0 + fB) * HD + h0 + c8B, tB);
#pragma unroll
        for (int e = 0; e < 8; ++e) sB[(c8B + e) * SA + fB] = tB[e];
        __syncthreads();
        short8 af = *(const short8*)(sA + (wave * 16 + m) * SA + ko);
#pragma unroll
        for (int ct = 0; ct < 4; ++ct) {
            short8 bf = *(const short8*)(sB + (ct * 16 + m) * SA + ko);
            acc[ct] = __builtin_amdgcn_mfma_f32_16x16x32_bf16(af, bf, acc[ct], 0, 0, 0);
        }
        __syncthreads();
    }
    unsigned short* yTk = yT + (size_t)k * HD * NN_;
#pragma unroll
    for (int ct = 0; ct < 4; ++ct)
#pragma unroll
        for (int r2 = 0; r2 < 4; ++r2) {
            int col = h0 + ct * 16 + m;
            int row = bi * 64 + wave * 16 + q * 4 + r2;
            yTk[(size_t)col * NN_ + row] = f2b(acc[ct][r2] * dinv[(size_t)k * NN_ + row]);
        }
}

// ---------------------------------------------------------------------------
// GEMM2 v2 (j-split): pbuf[s][k][i][h] = sum_{j in chunk s} A_k[i][j]*y_k[j][h]
//   (+ self y_k[i][h] folded into the chunk containing j==i)
// Block 64i x 128h x 1024j, waves 2x2 (wave = 32i x 64h), grid (2,64,4)=512.
// A deinterleaved to per-k LDS tiles at staging (vf4x3 -> 3 ds_write_b64).
// ---------------------------------------------------------------------------
__global__ __launch_bounds__(256) void gemm_agg(const float* __restrict__ adjf,
        const unsigned short* __restrict__ yT, unsigned short* __restrict__ pbuf) {
    __shared__ __align__(16) unsigned short sA[3][64 * PAG];   // [k][i][j] 15.4 KB
    __shared__ __align__(16) unsigned short sB[3][128 * PAG];  // [k][h][j] 30.7 KB
    const int bh = blockIdx.x, bi = blockIdx.y, s = blockIdx.z;
    const int t = threadIdx.x, lane = t & 63, wave = t >> 6;
    const int wi = wave & 1, wh = wave >> 1;
    const int m = lane & 15, q = lane >> 4, ko = q * 8;
    const int i0 = bi * 64, h0 = bh * 128, jbase = s * 1024;
    f32x4 acc[3][2][4] = {};
    for (int j0 = 0; j0 < 1024; j0 += 32) {
        // A stage: 64 rows x 32 j x 3 k; idx=g*256+t -> row=idx>>3, jq=(idx&7)*4
#pragma unroll
        for (int g = 0; g < 2; ++g) {
            int idx = g * 256 + t, row = idx >> 3, jq = (idx & 7) << 2;
            const float* src = adjf + (size_t)(i0 + row) * 12288 + (size_t)(jbase + j0 + jq) * 3;
            vf4 v0 = *(const vf4*)src, v1 = *(const vf4*)(src + 4), v2 = *(const vf4*)(src + 8);
            float vv[12] = {v0[0],v0[1],v0[2],v0[3],v1[0],v1[1],v1[2],v1[3],v2[0],v2[1],v2[2],v2[3]};
#pragma unroll
            for (int k = 0; k < 3; ++k) {
                vus4 w;
                w[0] = f2b(vv[0 + k]); w[1] = f2b(vv[3 + k]);
                w[2] = f2b(vv[6 + k]); w[3] = f2b(vv[9 + k]);
                *(vus4*)(&sA[k][row * PAG + jq]) = w;
            }
        }
        // B stage: 3k x 128h x 32j; e=it*256+t -> k=e>>9, h=(e&511)>>2, c=(e&3)*8
#pragma unroll
        for (int it = 0; it < 6; ++it) {
            int e = it * 256 + t, k = e >> 9, r = (e & 511) >> 2, c = (e & 3) << 3;
            *(vu4*)(&sB[k][r * PAG + c]) =
                *(const vu4*)(yT + (size_t)(k * 256 + h0 + r) * 4096 + jbase + j0 + c);
        }
        __syncthreads();
        short8 aF[3][2];
#pragma unroll
        for (int k = 0; k < 3; ++k)
#pragma unroll
            for (int rt = 0; rt < 2; ++rt)
                aF[k][rt] = *(const short8*)(&sA[k][(wi * 32 + rt * 16 + m) * PAG + ko]);
#pragma unroll
        for (int k = 0; k < 3; ++k)
#pragma unroll
            for (int ct = 0; ct < 4; ++ct) {
                short8 bF = *(const short8*)(&sB[k][(wh * 64 + ct * 16 + m) * PAG + ko]);
#pragma unroll
                for (int rt = 0; rt < 2; ++rt)
                    acc[k][rt][ct] = __builtin_amdgcn_mfma_f32_16x16x32_bf16(aF[k][rt], bF, acc[k][rt][ct], 0, 0, 0);
            }
        __syncthreads();
    }
    const int addself = (s == (i0 >> 10));   // chunk containing j == i (64 | 1024)
#pragma unroll
    for (int k = 0; k < 3; ++k)
#pragma unroll
        for (int rt = 0; rt < 2; ++rt)
#pragma unroll
            for (int ct = 0; ct < 4; ++ct)
#pragma unroll
                for (int r2 = 0; r2 < 4; ++r2) {
                    int row = i0 + wi * 32 + rt * 16 + q * 4 + r2;
                    int col = h0 + wh * 64 + ct * 16 + m;
                    float v = acc[k][rt][ct][r2];
                    if (addself) v += b2f(yT[((size_t)k * 256 + col) * 4096 + row]);
                    pbuf[(((size_t)s * 3 + k) * 4096 + row) * 256 + col] = f2b(v);
                }
}

// ---------------------------------------------------------------------------
// agg_reduce: xt[k][i][h] = f2b(dinv[k][i] * (sum_s pbuf[s]) + gnnb[k][h])
// ---------------------------------------------------------------------------
__global__ __launch_bounds__(256) void agg_reduce(const unsigned short* __restrict__ pbuf,
        const float* __restrict__ dinv, const float* __restrict__ gnnb,
        unsigned short* __restrict__ xt) {
    size_t e8 = ((size_t)blockIdx.x * 256 + threadIdx.x) * 8;  // over 3*4096*256
    int k = (int)(e8 >> 20);
    int i = (int)((e8 >> 8) & 4095);
    int h = (int)(e8 & 255);
    float di = dinv[k * NN_ + i];
    const size_t KIH = (size_t)KC * NN_ * HD;
    alignas(16) unsigned short p0[8], p1[8], p2[8], p3[8], o[8];
    *(vu4*)p0 = *(const vu4*)(pbuf + 0 * KIH + e8);
    *(vu4*)p1 = *(const vu4*)(pbuf + 1 * KIH + e8);
    *(vu4*)p2 = *(const vu4*)(pbuf + 2 * KIH + e8);
    *(vu4*)p3 = *(const vu4*)(pbuf + 3 * KIH + e8);
#pragma unroll
    for (int e = 0; e < 8; ++e) {
        float v = b2f(p0[e]) + b2f(p1[e]) + b2f(p2[e]) + b2f(p3[e]);
        o[e] = f2b(di * v + gnnb[k * HD + h + e]);
    }
    *(vu4*)(xt + e8) = *(vu4*)o;
}

// ---------------------------------------------------------------------------
// NT GEMM: out[k][n][col] = ep(A . W^T + b1 + b2); A,W bf16; b f32.
// gateX (COLS=1024, b_ih+b_hh) and fc (COLS=256, tanh).
// ---------------------------------------------------------------------------
__global__ __launch_bounds__(256) void gemm_nt_ep(const unsigned short* __restrict__ A,
        const unsigned short* __restrict__ W, const float* __restrict__ b1,
        const float* __restrict__ b2, unsigned short* __restrict__ outp,
        int COLS, int do_tanh) {
    __shared__ __align__(16) unsigned short sA[64 * SA], sB[64 * SA];
    const int bg = blockIdx.x, bn = blockIdx.y, k = blockIdx.z;
    const int t = threadIdx.x, lane = t & 63, wave = t >> 6;
    const int m = lane & 15, q = lane >> 4, ko = q * 8;
    f32x4 acc[4] = {};
    const unsigned short* A0 = A + ((size_t)k * NN_ + bn * 64) * HD;
    const unsigned short* W0 = W + ((size_t)k * COLS + bg * 64) * HD;
    const int r = t >> 2, c8 = (t & 3) << 3;
    for (int k0 = 0; k0 < HD; k0 += 32) {
        *(vu4*)(sA + r * SA + c8) = *(const vu4*)(A0 + (size_t)r * HD + k0 + c8);
        *(vu4*)(sB + r * SA + c8) = *(const vu4*)(W0 + (size_t)r * HD + k0 + c8);
        __syncthreads();
        short8 af = *(const short8*)(sA + (wave * 16 + m) * SA + ko);
#pragma unroll
        for (int ct = 0; ct < 4; ++ct) {
            short8 bf = *(const short8*)(sB + (ct * 16 + m) * SA + ko);
            acc[ct] = __builtin_amdgcn_mfma_f32_16x16x32_bf16(af, bf, acc[ct], 0, 0, 0);
        }
        __syncthreads();
    }
#pragma unroll
    for (int ct = 0; ct < 4; ++ct)
#pragma unroll
        for (int r2 = 0; r2 < 4; ++r2) {
            int col = bg * 64 + ct * 16 + m;
            int row = bn * 64 + wave * 16 + q * 4 + r2;
            float v = acc[ct][r2];
            if (b1) v += b1[(size_t)k * COLS + col];
            if (b2) v += b2[(size_t)k * COLS + col];
            if (do_tanh) v = tanhf(v);
            outp[((size_t)k * NN_ + row) * COLS + col] = f2b(v);
        }
}

// ---------------------------------------------------------------------------
// LSTM step, register-resident gates; whh bf16 (pre-converted); c state bf16.
// ---------------------------------------------------------------------------
__global__ __launch_bounds__(256) void lstm_step(const unsigned short* __restrict__ hprev,
        const unsigned short* __restrict__ whhb, const unsigned short* __restrict__ gateX,
        unsigned short* __restrict__ cbuf, unsigned short* __restrict__ hnext, int first) {
    __shared__ __align__(16) unsigned short sA[64 * SA];      // h_prev [row][k]
    __shared__ __align__(16) unsigned short sB[4][64 * SA];   // per gate [col][k]
    const int t = threadIdx.x, lane = t & 63, wave = t >> 6;
    const int m = lane & 15, q = lane >> 4, ko = q * 8;
    const int bc = blockIdx.x, bn = blockIdx.y, k = blockIdx.z;
    const int c0 = bc * 64;
    f32x4 acc[4][4] = {};   // [gate][col-tile]
    if (!first) {
        const unsigned short* A0 = hprev + ((size_t)k * NN_ + bn * 64) * HD;
        const unsigned short* W0 = whhb + (size_t)k * GD * HD;
        const int r = t >> 2, c8 = (t & 3) << 3;
        for (int k0 = 0; k0 < HD; k0 += 32) {
            *(vu4*)(sA + r * SA + c8) = *(const vu4*)(A0 + (size_t)r * HD + k0 + c8);
#pragma unroll
            for (int gt = 0; gt < 4; ++gt)
                *(vu4*)(&sB[gt][r * SA + c8]) =
                    *(const vu4*)(W0 + (size_t)(gt * 256 + c0 + r) * HD + k0 + c8);
            __syncthreads();
            short8 af = *(const short8*)(sA + (wave * 16 + m) * SA + ko);
#pragma unroll
            for (int gt = 0; gt < 4; ++gt)
#pragma unroll
                for (int ct = 0; ct < 4; ++ct) {
                    short8 bf = *(const short8*)(&sB[gt][(ct * 16 + m) * SA + ko]);
                    acc[gt][ct] = __builtin_amdgcn_mfma_f32_16x16x32_bf16(af, bf, acc[gt][ct], 0, 0, 0);
                }
            __syncthreads();
        }
    }
    const unsigned short* gX = gateX + ((size_t)k * NN_ + bn * 64) * GD;
    unsigned short* crow = cbuf + ((size_t)k * NN_ + bn * 64) * HD;
    unsigned short* hrow = hnext + ((size_t)k * NN_ + bn * 64) * HD;
#pragma unroll
    for (int ct = 0; ct < 4; ++ct)
#pragma unroll
        for (int r2 = 0; r2 < 4; ++r2) {
            int row = wave * 16 + q * 4 + r2;
            int col = c0 + ct * 16 + m;
            float iv = acc[0][ct][r2] + b2f(gX[(size_t)row * GD + 0 * 256 + col]);
            float fv = acc[1][ct][r2] + b2f(gX[(size_t)row * GD + 1 * 256 + col]);
            float gv = acc[2][ct][r2] + b2f(gX[(size_t)row * GD + 2 * 256 + col]);
            float ov = acc[3][ct][r2] + b2f(gX[(size_t)row * GD + 3 * 256 + col]);
            float cold = first ? 0.f : b2f(crow[(size_t)row * HD + col]);
            float cn = sigm(fv) * cold + sigm(iv) * tanhf(gv);
            float hn = sigm(ov) * tanhf(cn);
            crow[(size_t)row * HD + col] = f2b(cn);
            hrow[(size_t)row * HD + col] = f2b(hn);
        }
}

// ---------------------------------------------------------------------------
// final_ep: pred = sig_slice(x + mean_k delta); res[n][f][k] = sig_slice(x + delta_k)
// ---------------------------------------------------------------------------
__global__ __launch_bounds__(256) void final_ep(const float* __restrict__ x,
        const unsigned short* __restrict__ delta, float* __restrict__ pred,
        float* __restrict__ res) {
    int idx = blockIdx.x * 256 + threadIdx.x;
    size_t base = (size_t)idx * 8;
    int f0 = (int)(base & 255);
    alignas(16) unsigned short d0[8], d1[8], d2[8];
    alignas(16) float pr[8], rs[24];
    vf4 xa = *(const vf4*)(x + base), xb = *(const vf4*)(x + base + 4);
    float xs[8] = { xa[0], xa[1], xa[2], xa[3], xb[0], xb[1], xb[2], xb[3] };
    *(vu4*)d0 = *(const vu4*)(delta + base);
    *(vu4*)d1 = *(const vu4*)(delta + (size_t)NN_ * FD + base);
    *(vu4*)d2 = *(const vu4*)(delta + 2 * (size_t)NN_ * FD + base);
#pragma unroll
    for (int e = 0; e < 8; ++e) {
        int f = f0 + e;
        bool sg = (f >= 10) && (f < 253);
        float xf = xs[e];
        float da = b2f(d0[e]), db = b2f(d1[e]), dc = b2f(d2[e]);
        float dm = (da + db + dc) * (1.f / 3.f);
        float p = xf + dm; if (sg) p = sigm(p);
        pr[e] = p;
        float z0 = xf + da; if (sg) z0 = sigm(z0);
        float z1 = xf + db; if (sg) z1 = sigm(z1);
        float z2 = xf + dc; if (sg) z2 = sigm(z2);
        rs[e * 3 + 0] = z0; rs[e * 3 + 1] = z1; rs[e * 3 + 2] = z2;
    }
    *(vf4*)(pred + base)     = *(vf4*)pr;
    *(vf4*)(pred + base + 4) = *(vf4*)(pr + 4);
    size_t rb = base * 3;
#pragma unroll
    for (int v = 0; v < 6; ++v)
        *(vf4*)(res + rb + v * 4) = *(vf4*)(rs + v * 4);
}

extern "C" void kernel_launch(void* const* d_in, const int* in_sizes, int n_in,
                              void* d_out, int out_size, void* d_ws, size_t ws_size,
                              hipStream_t stream) {
    const float* x    = (const float*)d_in[0];
    const float* gnnw = (const float*)d_in[1];
    const float* gnnb = (const float*)d_in[2];
    const float* wih  = (const float*)d_in[3];
    const float* whh  = (const float*)d_in[4];
    const float* bih  = (const float*)d_in[5];
    const float* bhh  = (const float*)d_in[6];
    const float* fcw  = (const float*)d_in[7];
    const float* fcb  = (const float*)d_in[8];
    const int*   adj  = (const int*)d_in[9];

    float* out = (float*)d_out;
    float* out_pred = out;
    float* out_res  = out + (size_t)NN_ * FD;
    float* out_adj  = out + (size_t)NN_ * FD * 4;

    // ws layout (53.9 MB):
    //   dinv 48K | R1 (yT -> h even buf) 6M | R2 (xt -> delta) 6M | wb 3.5M |
    //   X: pbuf 25.2M (-> gateX 25.2M after reduce) | hA 6M | cbuf(bf16) 6M
    char* ws = (char*)d_ws;
    float*          dinv  = (float*)ws;                          // 49,152
    unsigned short* R1    = (unsigned short*)(ws + 49152);       // 6,291,456
    unsigned short* R2    = (unsigned short*)(ws + 6340608);     // 6,291,456
    unsigned short* wb    = (unsigned short*)(ws + 12632064);    // 3,538,944
    unsigned short* pbuf  = (unsigned short*)(ws + 16171008);    // 25,165,824
    unsigned short* gateX = pbuf;                                // same region, later lifetime
    unsigned short* hA    = (unsigned short*)(ws + 41336832);    // 6,291,456
    unsigned short* cbuf  = (unsigned short*)(ws + 47628288);    // 6,291,456 -> 53,919,744
    const unsigned short* wihb = wb;
    const unsigned short* whhb = wb + 786432;
    const unsigned short* fcwb = wb + 1572864;
    (void)ws_size; (void)in_sizes; (void)n_in; (void)out_size;

    wcvt<<<dim3(864), 256, 0, stream>>>(wih, whh, fcw, wb);
    adj_pass<<<dim3(4096), 256, 0, stream>>>(adj, out_adj, dinv);
    gemm_xw<<<dim3(64, 4, 3), 256, 0, stream>>>(x, gnnw, dinv, R1 /*yT*/);
    gemm_agg<<<dim3(2, 64, 4), 256, 0, stream>>>(out_adj, R1 /*yT*/, pbuf);
    agg_reduce<<<dim3(1536), 256, 0, stream>>>(pbuf, dinv, gnnb, R2 /*xt*/);
    gemm_nt_ep<<<dim3(16, 64, 3), 256, 0, stream>>>(R2 /*xt*/, wihb, bih, bhh, gateX, GD, 0);
    for (int tstep = 0; tstep < 5; ++tstep) {
        unsigned short* hp = (tstep & 1) ? R1 : hA;
        unsigned short* hn = (tstep & 1) ? hA : R1;
        lstm_step<<<dim3(4, 64, 3), 256, 0, stream>>>(hp, whhb, gateX, cbuf, hn, tstep == 0 ? 1 : 0);
    }
    gemm_nt_ep<<<dim3(4, 64, 3), 256, 0, stream>>>(R1 /*h_last*/, fcwb, fcb, nullptr, R2 /*delta*/, FD, 1);
    final_ep<<<dim3(512), 256, 0, stream>>>(x, R2 /*delta*/, out_pred, out_res);
}